// Round 4
// baseline (1842.575 us; speedup 1.0000x reference)
//
#include <hip/hip_runtime.h>
#include <math.h>

#define NTOK 8192
#define KCODES 8192
#define DDIM 512
#define QELEMS (NTOK * DDIM)
#define NCHUNK 8
#define CPC (KCODES / NCHUNK)   // codes per chunk = 1024

// Scratch lives inside d_out's quantized region (4,194,304 floats; we use
// < 600K). All scratch is consumed before gather() overwrites the region.
constexpr size_t S_PART  = 0;                    // 8192 tok * 8 chunks * 8 f
constexpr size_t S_XSQ   = 524288;               // 8192
constexpr size_t S_CSQ   = S_XSQ + NTOK;         // 8192
constexpr size_t S_LSE   = S_CSQ + KCODES;       // 8192
constexpr size_t S_PLOGP = S_LSE + NTOK;         // 8192
constexpr size_t S_D2    = S_PLOGP + NTOK;       // 8192
constexpr size_t S_AVG   = S_D2 + NTOK;          // 8192
constexpr size_t S_I1    = S_AVG + KCODES;       // 8192 (int bits)
constexpr size_t S_I2    = S_I1 + NTOK;          // 8192 (int bits)

__device__ __forceinline__ bool better(float v, int i, float v2, int i2) {
  return v > v2 || (v == v2 && i < i2);
}

// ---------------- squared norms ---------------------------------------------
__global__ __launch_bounds__(64) void sq_kernel(const float* __restrict__ x,
                                                const float* __restrict__ cb,
                                                float* __restrict__ dout) {
  const int row = blockIdx.x;  // 0..8191 codes, 8192..16383 tokens
  const int lane = threadIdx.x;
  const float* src = (row < KCODES) ? (cb + (size_t)row * DDIM)
                                    : (x + (size_t)(row - KCODES) * DDIM);
  float4 v0 = reinterpret_cast<const float4*>(src)[lane];
  float4 v1 = reinterpret_cast<const float4*>(src)[lane + 64];
  float s = v0.x*v0.x + v0.y*v0.y + v0.z*v0.z + v0.w*v0.w
          + v1.x*v1.x + v1.y*v1.y + v1.z*v1.z + v1.w*v1.w;
  #pragma unroll
  for (int o = 32; o; o >>= 1) s += __shfl_down(s, o);
  if (lane == 0) {
    if (row < KCODES) dout[S_CSQ + row] = s;
    else              dout[S_XSQ + (row - KCODES)] = s;
  }
}

__global__ void zero_kernel(float* __restrict__ dout) {
  dout[S_AVG + blockIdx.x * 256 + threadIdx.x] = 0.f;
}

// ---------------- pass 1: GEMM tile + fused online row stats ----------------
__global__ __launch_bounds__(256) void pass1_gemm(const float* __restrict__ x,
                                                  const float* __restrict__ cb,
                                                  float* __restrict__ dout) {
  __shared__ __align__(16) float As[16][132];
  __shared__ __align__(16) float Bs[16][132];
  const int tid = threadIdx.x;
  const int tx = tid & 15, ty = tid >> 4;
  const int m0 = blockIdx.y * 128;
  const int chunk = blockIdx.x;
  const int nbase = chunk * CPC;

  float xs[8];
  #pragma unroll
  for (int i = 0; i < 8; ++i)
    xs[i] = dout[S_XSQ + m0 + (i >> 2) * 64 + ty * 4 + (i & 3)];

  float rv1[8], rv2[8], rz[8], rs1[8];
  int ri1[8], ri2[8];
  #pragma unroll
  for (int i = 0; i < 8; ++i) {
    rv1[i] = -1e30f; rv2[i] = -1e30f; rz[i] = 0.f; rs1[i] = 0.f;
    ri1[i] = 0x7fffffff; ri2[i] = 0x7fffffff;
  }

  for (int st = 0; st < CPC / 128; ++st) {
    const int n0 = nbase + st * 128;
    float acc[8][8];
    #pragma unroll
    for (int i = 0; i < 8; ++i)
      #pragma unroll
      for (int j = 0; j < 8; ++j) acc[i][j] = 0.f;

    for (int kt = 0; kt < DDIM / 16; ++kt) {
      #pragma unroll
      for (int l = 0; l < 2; ++l) {
        const int idx = tid + l * 256;
        const int r = idx >> 2;
        const int c4 = (idx & 3) << 2;
        const float4 av = *reinterpret_cast<const float4*>(
            x + (size_t)(m0 + r) * DDIM + kt * 16 + c4);
        const float4 bv = *reinterpret_cast<const float4*>(
            cb + (size_t)(n0 + r) * DDIM + kt * 16 + c4);
        As[c4 + 0][r] = av.x; As[c4 + 1][r] = av.y;
        As[c4 + 2][r] = av.z; As[c4 + 3][r] = av.w;
        Bs[c4 + 0][r] = bv.x; Bs[c4 + 1][r] = bv.y;
        Bs[c4 + 2][r] = bv.z; Bs[c4 + 3][r] = bv.w;
      }
      __syncthreads();
      #pragma unroll
      for (int kk = 0; kk < 16; ++kk) {
        float a[8], b[8];
        *reinterpret_cast<float4*>(&a[0]) = *reinterpret_cast<const float4*>(&As[kk][ty * 4]);
        *reinterpret_cast<float4*>(&a[4]) = *reinterpret_cast<const float4*>(&As[kk][64 + ty * 4]);
        *reinterpret_cast<float4*>(&b[0]) = *reinterpret_cast<const float4*>(&Bs[kk][tx * 4]);
        *reinterpret_cast<float4*>(&b[4]) = *reinterpret_cast<const float4*>(&Bs[kk][64 + tx * 4]);
        #pragma unroll
        for (int i = 0; i < 8; ++i)
          #pragma unroll
          for (int j = 0; j < 8; ++j)
            acc[i][j] = fmaf(a[i], b[j], acc[i][j]);
      }
      __syncthreads();
    }

    // fused epilogue: online top-2 + softmax stats
    #pragma unroll
    for (int j = 0; j < 8; ++j) {
      const int c = n0 + (j >> 2) * 64 + tx * 4 + (j & 3);
      const float cs = dout[S_CSQ + c];
      #pragma unroll
      for (int i = 0; i < 8; ++i) {
        const float d2 = fmaxf(xs[i] - 2.f * acc[i][j] + cs, 0.f);
        const float f = -100.f * sqrtf(d2);
        if (f > rv1[i]) {
          const float a = __expf(rv1[i] - f);
          rs1[i] = a * (rs1[i] + (rv1[i] - f) * rz[i]);
          rz[i] = fmaf(a, rz[i], 1.0f);
          rv2[i] = rv1[i]; ri2[i] = ri1[i];
          rv1[i] = f; ri1[i] = c;
        } else {
          const float g = f - rv1[i];
          const float e = __expf(g);
          rz[i] += e;
          rs1[i] = fmaf(e, g, rs1[i]);
          if (f > rv2[i]) { rv2[i] = f; ri2[i] = c; }
        }
      }
    }
  }

  // merge across the 16 tx lanes (same 8 token rows)
  #pragma unroll
  for (int mask = 1; mask < 16; mask <<= 1) {
    #pragma unroll
    for (int i = 0; i < 8; ++i) {
      const float ov1 = __shfl_xor(rv1[i], mask);
      const float ov2 = __shfl_xor(rv2[i], mask);
      const float oz  = __shfl_xor(rz[i],  mask);
      const float os1 = __shfl_xor(rs1[i], mask);
      const int   oi1 = __shfl_xor(ri1[i], mask);
      const int   oi2 = __shfl_xor(ri2[i], mask);
      const float M = fmaxf(rv1[i], ov1);
      const float a = __expf(rv1[i] - M);
      const float b = __expf(ov1 - M);
      rs1[i] = a * (rs1[i] + (rv1[i] - M) * rz[i]) + b * (os1 + (ov1 - M) * oz);
      rz[i]  = a * rz[i] + b * oz;
      float n1, n2; int ni1, ni2;
      if (better(ov1, oi1, rv1[i], ri1[i])) {
        n1 = ov1; ni1 = oi1;
        if (better(rv1[i], ri1[i], ov2, oi2)) { n2 = rv1[i]; ni2 = ri1[i]; }
        else { n2 = ov2; ni2 = oi2; }
      } else {
        n1 = rv1[i]; ni1 = ri1[i];
        if (better(ov1, oi1, rv2[i], ri2[i])) { n2 = ov1; ni2 = oi1; }
        else { n2 = rv2[i]; ni2 = ri2[i]; }
      }
      rv1[i] = n1; ri1[i] = ni1; rv2[i] = n2; ri2[i] = ni2;
    }
  }

  if (tx == 0) {
    #pragma unroll
    for (int i = 0; i < 8; ++i) {
      const int t = m0 + (i >> 2) * 64 + ty * 4 + (i & 3);
      float* p = dout + S_PART + ((size_t)t * NCHUNK + chunk) * 8;
      p[0] = rv1[i]; p[1] = rz[i]; p[2] = rs1[i]; p[3] = rv2[i];
      p[4] = __int_as_float(ri1[i]); p[5] = __int_as_float(ri2[i]);
    }
  }
}

// ---------------- merge chunk partials per token ----------------------------
__global__ __launch_bounds__(256) void merge_rows(float* __restrict__ dout) {
  const int t = blockIdx.x * 256 + threadIdx.x;
  float v1 = -1e30f, v2 = -1e30f, z = 0.f, s1 = 0.f;
  int i1 = 0x7fffffff, i2 = 0x7fffffff;
  for (int c = 0; c < NCHUNK; ++c) {
    const float* p = dout + S_PART + ((size_t)t * NCHUNK + c) * 8;
    const float ov1 = p[0], oz = p[1], os1 = p[2], ov2 = p[3];
    const int oi1 = __float_as_int(p[4]), oi2 = __float_as_int(p[5]);
    const float M = fmaxf(v1, ov1);
    const float a = __expf(v1 - M);
    const float b = __expf(ov1 - M);
    s1 = a * (s1 + (v1 - M) * z) + b * (os1 + (ov1 - M) * oz);
    z  = a * z + b * oz;
    float n1, n2; int ni1, ni2;
    if (better(ov1, oi1, v1, i1)) {
      n1 = ov1; ni1 = oi1;
      if (better(v1, i1, ov2, oi2)) { n2 = v1; ni2 = i1; }
      else { n2 = ov2; ni2 = oi2; }
    } else {
      n1 = v1; ni1 = i1;
      if (better(ov1, oi1, v2, i2)) { n2 = ov1; ni2 = oi1; }
      else { n2 = v2; ni2 = i2; }
    }
    v1 = n1; i1 = ni1; v2 = n2; i2 = ni2;
  }
  const float lnZ = logf(z);
  dout[S_LSE + t] = v1 + lnZ;
  dout[S_PLOGP + t] = s1 / z - lnZ;
  reinterpret_cast<int*>(dout)[S_I1 + t] = i1;
  reinterpret_cast<int*>(dout)[S_I2 + t] = i2;
}

// ---------------- fp64 refinement of argmin over top-2 ----------------------
__global__ __launch_bounds__(64) void refine(const float* __restrict__ x,
                                             const float* __restrict__ cb,
                                             float* __restrict__ dout) {
  const int t = blockIdx.x;
  const int lane = threadIdx.x;
  const int i1 = reinterpret_cast<const int*>(dout)[S_I1 + t];
  const int i2 = reinterpret_cast<const int*>(dout)[S_I2 + t];
  const float* xt = x + (size_t)t * DDIM;
  const float* c1 = cb + (size_t)i1 * DDIM;
  const float* c2 = cb + (size_t)i2 * DDIM;
  double d1 = 0.0, d2 = 0.0;
  #pragma unroll
  for (int j = 0; j < DDIM / 64; ++j) {
    const int d = j * 64 + lane;
    const double xv = (double)xt[d];
    const double u = xv - (double)c1[d];
    const double w = xv - (double)c2[d];
    d1 += u * u;
    d2 += w * w;
  }
  #pragma unroll
  for (int o = 32; o; o >>= 1) { d1 += __shfl_down(d1, o); d2 += __shfl_down(d2, o); }
  if (lane == 0) {
    const bool pick2 = (d2 < d1) || (d2 == d1 && i2 < i1);
    dout[S_D2 + t] = (float)(pick2 ? d2 : d1);
    dout[(size_t)QELEMS + 4 + t] = (float)(pick2 ? i2 : i1);
  }
}

// ---------------- pass 2: recompute GEMM, accumulate avg_probs columns ------
__global__ __launch_bounds__(256) void col_gemm(const float* __restrict__ x,
                                                const float* __restrict__ cb,
                                                float* __restrict__ dout) {
  __shared__ __align__(16) float As[16][132];
  __shared__ __align__(16) float Bs[16][132];
  __shared__ float red[16][128];
  const int tid = threadIdx.x;
  const int tx = tid & 15, ty = tid >> 4;
  const int m0 = blockIdx.y * 128;
  const int nbase = blockIdx.x * CPC;

  float xs[8], lse[8];
  #pragma unroll
  for (int i = 0; i < 8; ++i) {
    const int r = m0 + (i >> 2) * 64 + ty * 4 + (i & 3);
    xs[i] = dout[S_XSQ + r];
    lse[i] = dout[S_LSE + r];
  }

  for (int st = 0; st < CPC / 128; ++st) {
    const int n0 = nbase + st * 128;
    float acc[8][8];
    #pragma unroll
    for (int i = 0; i < 8; ++i)
      #pragma unroll
      for (int j = 0; j < 8; ++j) acc[i][j] = 0.f;

    for (int kt = 0; kt < DDIM / 16; ++kt) {
      #pragma unroll
      for (int l = 0; l < 2; ++l) {
        const int idx = tid + l * 256;
        const int r = idx >> 2;
        const int c4 = (idx & 3) << 2;
        const float4 av = *reinterpret_cast<const float4*>(
            x + (size_t)(m0 + r) * DDIM + kt * 16 + c4);
        const float4 bv = *reinterpret_cast<const float4*>(
            cb + (size_t)(n0 + r) * DDIM + kt * 16 + c4);
        As[c4 + 0][r] = av.x; As[c4 + 1][r] = av.y;
        As[c4 + 2][r] = av.z; As[c4 + 3][r] = av.w;
        Bs[c4 + 0][r] = bv.x; Bs[c4 + 1][r] = bv.y;
        Bs[c4 + 2][r] = bv.z; Bs[c4 + 3][r] = bv.w;
      }
      __syncthreads();
      #pragma unroll
      for (int kk = 0; kk < 16; ++kk) {
        float a[8], b[8];
        *reinterpret_cast<float4*>(&a[0]) = *reinterpret_cast<const float4*>(&As[kk][ty * 4]);
        *reinterpret_cast<float4*>(&a[4]) = *reinterpret_cast<const float4*>(&As[kk][64 + ty * 4]);
        *reinterpret_cast<float4*>(&b[0]) = *reinterpret_cast<const float4*>(&Bs[kk][tx * 4]);
        *reinterpret_cast<float4*>(&b[4]) = *reinterpret_cast<const float4*>(&Bs[kk][64 + tx * 4]);
        #pragma unroll
        for (int i = 0; i < 8; ++i)
          #pragma unroll
          for (int j = 0; j < 8; ++j)
            acc[i][j] = fmaf(a[i], b[j], acc[i][j]);
      }
      __syncthreads();
    }

    // epilogue: column partial sums of exp(f - lse)
    #pragma unroll
    for (int j = 0; j < 8; ++j) {
      const int cl = (j >> 2) * 64 + tx * 4 + (j & 3);
      const float cs = dout[S_CSQ + n0 + cl];
      float cp = 0.f;
      #pragma unroll
      for (int i = 0; i < 8; ++i) {
        const float d2 = fmaxf(xs[i] - 2.f * acc[i][j] + cs, 0.f);
        const float f = -100.f * sqrtf(d2);
        cp += __expf(f - lse[i]);
      }
      red[ty][cl] = cp;
    }
    __syncthreads();
    #pragma unroll
    for (int s = 8; s >= 1; s >>= 1) {
      if (ty < s) {
        #pragma unroll
        for (int j = 0; j < 8; ++j) {
          const int cl = (j >> 2) * 64 + tx * 4 + (j & 3);
          red[ty][cl] += red[ty + s][cl];
        }
      }
      __syncthreads();
    }
    if (tid < 128) atomicAdd(&dout[S_AVG + n0 + tid], red[0][tid]);
    __syncthreads();
  }
}

// ---------------- finalize scalars ------------------------------------------
__global__ __launch_bounds__(256) void finalize(float* __restrict__ dout) {
  const int tid = threadIdx.x;
  float ent = 0.f, sp = 0.f, sd = 0.f;
  for (int j = 0; j < KCODES / 256; ++j) {
    const float a = dout[S_AVG + j * 256 + tid] * (1.0f / (float)NTOK);
    ent -= a * logf(a + 1e-8f);
    sp += dout[S_PLOGP + j * 256 + tid];
    sd += dout[S_D2 + j * 256 + tid];
  }
  __shared__ float se[256], sP[256], sD[256];
  se[tid] = ent; sP[tid] = sp; sD[tid] = sd;
  __syncthreads();
  for (int s = 128; s > 0; s >>= 1) {
    if (tid < s) { se[tid] += se[tid + s]; sP[tid] += sP[tid + s]; sD[tid] += sD[tid + s]; }
    __syncthreads();
  }
  if (tid == 0) {
    const float avg_entropy = se[0];
    const float sample_entropy = -sP[0] / (float)NTOK;
    const float entropy_loss = (sample_entropy - avg_entropy) * 0.1f;
    const float mse = sD[0] / (float)QELEMS;
    const float commit = 0.5f * mse * 0.25f;
    const float cbl = 0.5f * mse;
    dout[QELEMS + 0] = cbl + commit + entropy_loss;
    dout[QELEMS + 1] = commit;
    dout[QELEMS + 2] = cbl;
    dout[QELEMS + 3] = entropy_loss;
  }
}

// ---------------- gather quantized_st (runs last; scratch now dead) ---------
__global__ __launch_bounds__(128) void gather_kernel(const float* __restrict__ x,
                                                     const float* __restrict__ cb,
                                                     float* __restrict__ dout) {
  const int t = blockIdx.x;
  const int tid = threadIdx.x;
  const int idx = (int)dout[(size_t)QELEMS + 4 + t];
  const float4 xv = reinterpret_cast<const float4*>(x + (size_t)t * DDIM)[tid];
  const float4 cv = reinterpret_cast<const float4*>(cb + (size_t)idx * DDIM)[tid];
  float4 o;
  o.x = xv.x + (cv.x - xv.x);
  o.y = xv.y + (cv.y - xv.y);
  o.z = xv.z + (cv.z - xv.z);
  o.w = xv.w + (cv.w - xv.w);
  reinterpret_cast<float4*>(dout + (size_t)t * DDIM)[tid] = o;
}

extern "C" void kernel_launch(void* const* d_in, const int* in_sizes, int n_in,
                              void* d_out, int out_size, void* d_ws, size_t ws_size,
                              hipStream_t stream) {
  const float* x = (const float*)d_in[0];    // (4,2048,512)
  const float* cb = (const float*)d_in[1];   // (8192,512)
  float* dout = (float*)d_out;

  sq_kernel<<<KCODES + NTOK, 64, 0, stream>>>(x, cb, dout);
  zero_kernel<<<KCODES / 256, 256, 0, stream>>>(dout);
  pass1_gemm<<<dim3(NCHUNK, NTOK / 128), 256, 0, stream>>>(x, cb, dout);
  merge_rows<<<NTOK / 256, 256, 0, stream>>>(dout);
  refine<<<NTOK, 64, 0, stream>>>(x, cb, dout);
  col_gemm<<<dim3(NCHUNK, NTOK / 128), 256, 0, stream>>>(x, cb, dout);
  finalize<<<1, 256, 0, stream>>>(dout);
  gather_kernel<<<NTOK, 128, 0, stream>>>(x, cb, dout);
}

// Round 6
// 947.972 us; speedup vs baseline: 1.9437x; 1.9437x over previous
//
#include <hip/hip_runtime.h>
#include <math.h>

#define NTOK 8192
#define KCODES 8192
#define DDIM 512
#define QELEMS (NTOK * DDIM)
#define NCHUNK 8
#define CPC (KCODES / NCHUNK)   // codes per chunk = 1024
#define LDK 40                  // padded LDS K-stride in shorts (2-way conflict = free)

// Scratch lives inside d_out's quantized region (4,194,304 floats; we use
// < 600K). All scratch is consumed before gather() overwrites the region.
constexpr size_t S_PART  = 0;                    // 8192 tok * 8 chunks * 8 f
constexpr size_t S_XSQ   = 524288;               // 8192
constexpr size_t S_CSQ   = S_XSQ + NTOK;         // 8192
constexpr size_t S_LSE   = S_CSQ + KCODES;       // 8192
constexpr size_t S_PLOGP = S_LSE + NTOK;         // 8192
constexpr size_t S_D2    = S_PLOGP + NTOK;       // 8192
constexpr size_t S_AVG   = S_D2 + NTOK;          // 8192
constexpr size_t S_I1    = S_AVG + KCODES;       // 8192 (int bits)
constexpr size_t S_I2    = S_I1 + NTOK;          // 8192 (int bits)

typedef __attribute__((ext_vector_type(8))) short bf16x8;
typedef __attribute__((ext_vector_type(4))) float f32x4;

__device__ __forceinline__ bool better(float v, int i, float v2, int i2) {
  return v > v2 || (v == v2 && i < i2);
}

// fp32 -> (hi, lo) bf16 pair by truncation; hi+lo carries ~17 mantissa bits
__device__ __forceinline__ void cvt_hilo(float f, unsigned& h, unsigned& l) {
  const unsigned u = __float_as_uint(f);
  h = u >> 16;
  const float lf = f - __uint_as_float(u & 0xFFFF0000u);
  l = __float_as_uint(lf) >> 16;
}

// ---------------- squared norms ---------------------------------------------
__global__ __launch_bounds__(64) void sq_kernel(const float* __restrict__ x,
                                                const float* __restrict__ cb,
                                                float* __restrict__ dout) {
  const int row = blockIdx.x;  // 0..8191 codes, 8192..16383 tokens
  const int lane = threadIdx.x;
  const float* src = (row < KCODES) ? (cb + (size_t)row * DDIM)
                                    : (x + (size_t)(row - KCODES) * DDIM);
  float4 v0 = reinterpret_cast<const float4*>(src)[lane];
  float4 v1 = reinterpret_cast<const float4*>(src)[lane + 64];
  float s = v0.x*v0.x + v0.y*v0.y + v0.z*v0.z + v0.w*v0.w
          + v1.x*v1.x + v1.y*v1.y + v1.z*v1.z + v1.w*v1.w;
  #pragma unroll
  for (int o = 32; o; o >>= 1) s += __shfl_down(s, o);
  if (lane == 0) {
    if (row < KCODES) dout[S_CSQ + row] = s;
    else              dout[S_XSQ + (row - KCODES)] = s;
  }
}

__global__ void zero_kernel(float* __restrict__ dout) {
  dout[S_AVG + blockIdx.x * 256 + threadIdx.x] = 0.f;
}

// Staging: fp32 tile -> bf16 hi/lo LDS tiles (shared by both GEMM kernels)
#define STAGE_TILES(kt_)                                                      \
  {                                                                           \
    const int kb = (kt_) * 32 + sc;                                           \
    _Pragma("unroll")                                                         \
    for (int rep = 0; rep < 4; ++rep) {                                       \
      const int row = sr + rep * 32;                                          \
      const float4 av = *reinterpret_cast<const float4*>(                     \
          x + (size_t)(m0 + row) * DDIM + kb);                                \
      const float4 bv = *reinterpret_cast<const float4*>(                     \
          cb + (size_t)(n0 + row) * DDIM + kb);                               \
      unsigned h0, h1, h2, h3, l0, l1, l2, l3;                                \
      uint2 t;                                                                \
      cvt_hilo(av.x, h0, l0); cvt_hilo(av.y, h1, l1);                         \
      cvt_hilo(av.z, h2, l2); cvt_hilo(av.w, h3, l3);                         \
      t.x = h0 | (h1 << 16); t.y = h2 | (h3 << 16);                           \
      *reinterpret_cast<uint2*>(&Ah[row][sc]) = t;                            \
      t.x = l0 | (l1 << 16); t.y = l2 | (l3 << 16);                           \
      *reinterpret_cast<uint2*>(&Al[row][sc]) = t;                            \
      cvt_hilo(bv.x, h0, l0); cvt_hilo(bv.y, h1, l1);                         \
      cvt_hilo(bv.z, h2, l2); cvt_hilo(bv.w, h3, l3);                         \
      t.x = h0 | (h1 << 16); t.y = h2 | (h3 << 16);                           \
      *reinterpret_cast<uint2*>(&Bh[row][sc]) = t;                            \
      t.x = l0 | (l1 << 16); t.y = l2 | (l3 << 16);                           \
      *reinterpret_cast<uint2*>(&Bl[row][sc]) = t;                            \
    }                                                                         \
  }

#define MFMA_KSTEP                                                            \
  {                                                                           \
    bf16x8 a_h[4], a_l[4];                                                    \
    _Pragma("unroll")                                                         \
    for (int fi = 0; fi < 4; ++fi) {                                          \
      a_h[fi] = *reinterpret_cast<const bf16x8*>(&Ah[ar + fi * 16][koff]);    \
      a_l[fi] = *reinterpret_cast<const bf16x8*>(&Al[ar + fi * 16][koff]);    \
    }                                                                         \
    _Pragma("unroll")                                                         \
    for (int fj = 0; fj < 4; ++fj) {                                          \
      const bf16x8 b_h = *reinterpret_cast<const bf16x8*>(&Bh[br + fj * 16][koff]); \
      const bf16x8 b_l = *reinterpret_cast<const bf16x8*>(&Bl[br + fj * 16][koff]); \
      _Pragma("unroll")                                                       \
      for (int fi = 0; fi < 4; ++fi) {                                        \
        acc[fi][fj] = __builtin_amdgcn_mfma_f32_16x16x32_bf16(a_h[fi], b_h, acc[fi][fj], 0, 0, 0); \
        acc[fi][fj] = __builtin_amdgcn_mfma_f32_16x16x32_bf16(a_l[fi], b_h, acc[fi][fj], 0, 0, 0); \
        acc[fi][fj] = __builtin_amdgcn_mfma_f32_16x16x32_bf16(a_h[fi], b_l, acc[fi][fj], 0, 0, 0); \
      }                                                                       \
    }                                                                         \
  }

// ---------------- pass 1: split-bf16 MFMA GEMM + fused online row stats -----
__global__ __launch_bounds__(256) void pass1_mfma(const float* __restrict__ x,
                                                  const float* __restrict__ cb,
                                                  float* __restrict__ dout) {
  __shared__ short Ah[128][LDK], Al[128][LDK], Bh[128][LDK], Bl[128][LDK];
  __shared__ float stats[2][128][6];  // [wc][row]{m, z, s1, v2, i1, i2}
  const int tid = threadIdx.x;
  const int l = tid & 63;
  const int w = tid >> 6;
  const int wr = w >> 1, wc = w & 1;
  const int g = l >> 4, lx = l & 15;
  const int ar = wr * 64 + lx;
  const int br = wc * 64 + lx;
  const int koff = g * 8;
  const int sr = tid >> 3;            // staging row 0..31
  const int sc = (tid & 7) * 4;       // staging col 0..28
  const int m0 = blockIdx.y * 128;
  const int chunk = blockIdx.x;

  if (tid < 128) {
    #pragma unroll
    for (int q = 0; q < 2; ++q) {
      stats[q][tid][0] = -1e30f; stats[q][tid][1] = 0.f; stats[q][tid][2] = 0.f;
      stats[q][tid][3] = -1e30f;
      stats[q][tid][4] = __int_as_float(0x7fffffff);
      stats[q][tid][5] = __int_as_float(0x7fffffff);
    }
  }

  float xs[16];
  #pragma unroll
  for (int fi = 0; fi < 4; ++fi)
    #pragma unroll
    for (int v = 0; v < 4; ++v)
      xs[fi * 4 + v] = dout[S_XSQ + m0 + wr * 64 + fi * 16 + g * 4 + v];

  for (int st = 0; st < CPC / 128; ++st) {
    const int n0 = chunk * CPC + st * 128;
    f32x4 acc[4][4];
    #pragma unroll
    for (int fi = 0; fi < 4; ++fi)
      #pragma unroll
      for (int fj = 0; fj < 4; ++fj)
        acc[fi][fj] = (f32x4){0.f, 0.f, 0.f, 0.f};

    for (int kt = 0; kt < DDIM / 32; ++kt) {
      __syncthreads();
      STAGE_TILES(kt);
      __syncthreads();
      MFMA_KSTEP;
    }

    // fused epilogue: per-row online softmax stats + top-2
    const int colbase = n0 + wc * 64 + lx;
    float cs[4];
    #pragma unroll
    for (int fj = 0; fj < 4; ++fj) cs[fj] = dout[S_CSQ + colbase + fj * 16];

    #pragma unroll
    for (int fi = 0; fi < 4; ++fi) {
      #pragma unroll
      for (int v = 0; v < 4; ++v) {
        const float xsv = xs[fi * 4 + v];
        float fv[4];
        #pragma unroll
        for (int fj = 0; fj < 4; ++fj) {
          const float d2 = fmaxf(fmaf(-2.f, acc[fi][fj][v], xsv) + cs[fj], 0.f);
          fv[fj] = -100.f * sqrtf(d2);
        }
        // lane-local top2 of 4
        float v1 = fv[0], v2 = -1e30f;
        int i1 = colbase, i2 = 0x7fffffff;
        #pragma unroll
        for (int fj = 1; fj < 4; ++fj) {
          const int c = colbase + fj * 16;
          if (better(fv[fj], c, v1, i1)) { v2 = v1; i2 = i1; v1 = fv[fj]; i1 = c; }
          else if (better(fv[fj], c, v2, i2)) { v2 = fv[fj]; i2 = c; }
        }
        // merge top2 across the 16 lanes holding this row
        #pragma unroll
        for (int mask = 1; mask < 16; mask <<= 1) {
          const float ov1 = __shfl_xor(v1, mask);
          const float ov2 = __shfl_xor(v2, mask);
          const int oi1 = __shfl_xor(i1, mask);
          const int oi2 = __shfl_xor(i2, mask);
          float n1, n2; int ni1, ni2;
          if (better(ov1, oi1, v1, i1)) {
            n1 = ov1; ni1 = oi1;
            if (better(v1, i1, ov2, oi2)) { n2 = v1; ni2 = i1; } else { n2 = ov2; ni2 = oi2; }
          } else {
            n1 = v1; ni1 = i1;
            if (better(ov1, oi1, v2, i2)) { n2 = ov1; ni2 = oi1; } else { n2 = v2; ni2 = i2; }
          }
          v1 = n1; i1 = ni1; v2 = n2; i2 = ni2;
        }
        // v1 is now the row max over these 64 cols; exp-sums relative to it
        float z = 0.f, s = 0.f;
        #pragma unroll
        for (int fj = 0; fj < 4; ++fj) {
          const float ge = fv[fj] - v1;
          const float e = __expf(ge);
          z += e; s = fmaf(e, ge, s);
        }
        #pragma unroll
        for (int mask = 1; mask < 16; mask <<= 1) {
          z += __shfl_xor(z, mask);
          s += __shfl_xor(s, mask);
        }
        if (lx == 0) {
          const int r = wr * 64 + fi * 16 + g * 4 + v;
          float* st_ = &stats[wc][r][0];
          const float ov1 = st_[0], oz = st_[1], os = st_[2], ov2 = st_[3];
          const int oi1 = __float_as_int(st_[4]), oi2 = __float_as_int(st_[5]);
          const float M = fmaxf(v1, ov1);
          const float ea = __expf(v1 - M), eb = __expf(ov1 - M);
          st_[1] = ea * z + eb * oz;
          st_[2] = ea * (s + (v1 - M) * z) + eb * (os + (ov1 - M) * oz);
          float n1, n2; int ni1, ni2;
          if (better(ov1, oi1, v1, i1)) {
            n1 = ov1; ni1 = oi1;
            if (better(v1, i1, ov2, oi2)) { n2 = v1; ni2 = i1; } else { n2 = ov2; ni2 = oi2; }
          } else {
            n1 = v1; ni1 = i1;
            if (better(ov1, oi1, v2, i2)) { n2 = ov1; ni2 = oi1; } else { n2 = v2; ni2 = i2; }
          }
          st_[0] = n1; st_[3] = n2;
          st_[4] = __int_as_float(ni1);
          st_[5] = __int_as_float(ni2);
        }
      }
    }
  }

  __syncthreads();
  if (tid < 128) {
    float v1 = stats[0][tid][0], z = stats[0][tid][1], s = stats[0][tid][2], v2 = stats[0][tid][3];
    int i1 = __float_as_int(stats[0][tid][4]), i2 = __float_as_int(stats[0][tid][5]);
    const float ov1 = stats[1][tid][0], oz = stats[1][tid][1];
    const float os = stats[1][tid][2], ov2 = stats[1][tid][3];
    const int oi1 = __float_as_int(stats[1][tid][4]), oi2 = __float_as_int(stats[1][tid][5]);
    const float M = fmaxf(v1, ov1);
    const float ea = __expf(v1 - M), eb = __expf(ov1 - M);
    const float nz = ea * z + eb * oz;
    const float ns = ea * (s + (v1 - M) * z) + eb * (os + (ov1 - M) * oz);
    float n1, n2; int ni1, ni2;
    if (better(ov1, oi1, v1, i1)) {
      n1 = ov1; ni1 = oi1;
      if (better(v1, i1, ov2, oi2)) { n2 = v1; ni2 = i1; } else { n2 = ov2; ni2 = oi2; }
    } else {
      n1 = v1; ni1 = i1;
      if (better(ov1, oi1, v2, i2)) { n2 = ov1; ni2 = oi1; } else { n2 = v2; ni2 = i2; }
    }
    float* p = dout + S_PART + ((size_t)(m0 + tid) * NCHUNK + chunk) * 8;
    p[0] = n1; p[1] = nz; p[2] = ns; p[3] = n2;
    p[4] = __int_as_float(ni1); p[5] = __int_as_float(ni2);
  }
}

// ---------------- merge chunk partials per token ----------------------------
__global__ __launch_bounds__(256) void merge_rows(float* __restrict__ dout) {
  const int t = blockIdx.x * 256 + threadIdx.x;
  float v1 = -1e30f, v2 = -1e30f, z = 0.f, s1 = 0.f;
  int i1 = 0x7fffffff, i2 = 0x7fffffff;
  for (int c = 0; c < NCHUNK; ++c) {
    const float* p = dout + S_PART + ((size_t)t * NCHUNK + c) * 8;
    const float ov1 = p[0], oz = p[1], os1 = p[2], ov2 = p[3];
    const int oi1 = __float_as_int(p[4]), oi2 = __float_as_int(p[5]);
    const float M = fmaxf(v1, ov1);
    const float a = __expf(v1 - M);
    const float b = __expf(ov1 - M);
    s1 = a * (s1 + (v1 - M) * z) + b * (os1 + (ov1 - M) * oz);
    z  = a * z + b * oz;
    float n1, n2; int ni1, ni2;
    if (better(ov1, oi1, v1, i1)) {
      n1 = ov1; ni1 = oi1;
      if (better(v1, i1, ov2, oi2)) { n2 = v1; ni2 = i1; }
      else { n2 = ov2; ni2 = oi2; }
    } else {
      n1 = v1; ni1 = i1;
      if (better(ov1, oi1, v2, i2)) { n2 = ov1; ni2 = oi1; }
      else { n2 = v2; ni2 = i2; }
    }
    v1 = n1; i1 = ni1; v2 = n2; i2 = ni2;
  }
  const float lnZ = logf(z);
  dout[S_LSE + t] = v1 + lnZ;
  dout[S_PLOGP + t] = s1 / z - lnZ;
  reinterpret_cast<int*>(dout)[S_I1 + t] = i1;
  reinterpret_cast<int*>(dout)[S_I2 + t] = i2;
}

// ---------------- fp64 refinement of argmin over top-2 ----------------------
__global__ __launch_bounds__(64) void refine(const float* __restrict__ x,
                                             const float* __restrict__ cb,
                                             float* __restrict__ dout) {
  const int t = blockIdx.x;
  const int lane = threadIdx.x;
  const int i1 = reinterpret_cast<const int*>(dout)[S_I1 + t];
  const int i2 = reinterpret_cast<const int*>(dout)[S_I2 + t];
  const float* xt = x + (size_t)t * DDIM;
  const float* c1 = cb + (size_t)i1 * DDIM;
  const float* c2 = cb + (size_t)i2 * DDIM;
  double d1 = 0.0, d2 = 0.0;
  #pragma unroll
  for (int j = 0; j < DDIM / 64; ++j) {
    const int d = j * 64 + lane;
    const double xv = (double)xt[d];
    const double u = xv - (double)c1[d];
    const double w = xv - (double)c2[d];
    d1 += u * u;
    d2 += w * w;
  }
  #pragma unroll
  for (int o = 32; o; o >>= 1) { d1 += __shfl_down(d1, o); d2 += __shfl_down(d2, o); }
  if (lane == 0) {
    const bool pick2 = (d2 < d1) || (d2 == d1 && i2 < i1);
    dout[S_D2 + t] = (float)(pick2 ? d2 : d1);
    dout[(size_t)QELEMS + 4 + t] = (float)(pick2 ? i2 : i1);
  }
}

// ---------------- pass 2: split-bf16 MFMA GEMM + avg_probs column sums ------
__global__ __launch_bounds__(256) void col_mfma(const float* __restrict__ x,
                                                const float* __restrict__ cb,
                                                float* __restrict__ dout) {
  __shared__ short Ah[128][LDK], Al[128][LDK], Bh[128][LDK], Bl[128][LDK];
  __shared__ float red[4][64];
  const int tid = threadIdx.x;
  const int l = tid & 63;
  const int w = tid >> 6;
  const int wr = w >> 1, wc = w & 1;
  const int g = l >> 4, lx = l & 15;
  const int ar = wr * 64 + lx;
  const int br = wc * 64 + lx;
  const int koff = g * 8;
  const int sr = tid >> 3;
  const int sc = (tid & 7) * 4;
  const int m0 = blockIdx.y * 128;
  const int chunk = blockIdx.x;

  float xs[16], lse[16];
  #pragma unroll
  for (int fi = 0; fi < 4; ++fi)
    #pragma unroll
    for (int v = 0; v < 4; ++v) {
      const int r = m0 + wr * 64 + fi * 16 + g * 4 + v;
      xs[fi * 4 + v] = dout[S_XSQ + r];
      lse[fi * 4 + v] = dout[S_LSE + r];
    }

  for (int st = 0; st < CPC / 128; ++st) {
    const int n0 = chunk * CPC + st * 128;
    f32x4 acc[4][4];
    #pragma unroll
    for (int fi = 0; fi < 4; ++fi)
      #pragma unroll
      for (int fj = 0; fj < 4; ++fj)
        acc[fi][fj] = (f32x4){0.f, 0.f, 0.f, 0.f};

    for (int kt = 0; kt < DDIM / 32; ++kt) {
      __syncthreads();
      STAGE_TILES(kt);
      __syncthreads();
      MFMA_KSTEP;
    }

    const int colbase = n0 + wc * 64 + lx;
    float cs[4];
    #pragma unroll
    for (int fj = 0; fj < 4; ++fj) cs[fj] = dout[S_CSQ + colbase + fj * 16];

    float colsum[4] = {0.f, 0.f, 0.f, 0.f};
    #pragma unroll
    for (int fi = 0; fi < 4; ++fi) {
      #pragma unroll
      for (int v = 0; v < 4; ++v) {
        const float xsv = xs[fi * 4 + v];
        const float lsev = lse[fi * 4 + v];
        #pragma unroll
        for (int fj = 0; fj < 4; ++fj) {
          const float d2 = fmaxf(fmaf(-2.f, acc[fi][fj][v], xsv) + cs[fj], 0.f);
          const float f = -100.f * sqrtf(d2);
          colsum[fj] += __expf(f - lsev);
        }
      }
    }
    #pragma unroll
    for (int fj = 0; fj < 4; ++fj) {
      colsum[fj] += __shfl_xor(colsum[fj], 16);
      colsum[fj] += __shfl_xor(colsum[fj], 32);
    }
    __syncthreads();
    if (g == 0) {
      #pragma unroll
      for (int fj = 0; fj < 4; ++fj) red[w][fj * 16 + lx] = colsum[fj];
    }
    __syncthreads();
    if (tid < 128) {
      const int wcc = tid >> 6, c = tid & 63;
      atomicAdd(&dout[S_AVG + n0 + tid], red[wcc][c] + red[wcc + 2][c]);
    }
  }
}

// ---------------- finalize scalars ------------------------------------------
__global__ __launch_bounds__(256) void finalize(float* __restrict__ dout) {
  const int tid = threadIdx.x;
  float ent = 0.f, sp = 0.f, sd = 0.f;
  for (int j = 0; j < KCODES / 256; ++j) {
    const float a = dout[S_AVG + j * 256 + tid] * (1.0f / (float)NTOK);
    ent -= a * logf(a + 1e-8f);
    sp += dout[S_PLOGP + j * 256 + tid];
    sd += dout[S_D2 + j * 256 + tid];
  }
  __shared__ float se[256], sP[256], sD[256];
  se[tid] = ent; sP[tid] = sp; sD[tid] = sd;
  __syncthreads();
  for (int s = 128; s > 0; s >>= 1) {
    if (tid < s) { se[tid] += se[tid + s]; sP[tid] += sP[tid + s]; sD[tid] += sD[tid + s]; }
    __syncthreads();
  }
  if (tid == 0) {
    const float avg_entropy = se[0];
    const float sample_entropy = -sP[0] / (float)NTOK;
    const float entropy_loss = (sample_entropy - avg_entropy) * 0.1f;
    const float mse = sD[0] / (float)QELEMS;
    const float commit = 0.5f * mse * 0.25f;
    const float cbl = 0.5f * mse;
    dout[QELEMS + 0] = cbl + commit + entropy_loss;
    dout[QELEMS + 1] = commit;
    dout[QELEMS + 2] = cbl;
    dout[QELEMS + 3] = entropy_loss;
  }
}

// ---------------- gather quantized_st (runs last; scratch now dead) ---------
__global__ __launch_bounds__(128) void gather_kernel(const float* __restrict__ x,
                                                     const float* __restrict__ cb,
                                                     float* __restrict__ dout) {
  const int t = blockIdx.x;
  const int tid = threadIdx.x;
  const int idx = (int)dout[(size_t)QELEMS + 4 + t];
  const float4 cv = reinterpret_cast<const float4*>(cb + (size_t)idx * DDIM)[tid];
  reinterpret_cast<float4*>(dout + (size_t)t * DDIM)[tid] = cv;
}

extern "C" void kernel_launch(void* const* d_in, const int* in_sizes, int n_in,
                              void* d_out, int out_size, void* d_ws, size_t ws_size,
                              hipStream_t stream) {
  const float* x = (const float*)d_in[0];    // (4,2048,512)
  const float* cb = (const float*)d_in[1];   // (8192,512)
  float* dout = (float*)d_out;

  sq_kernel<<<KCODES + NTOK, 64, 0, stream>>>(x, cb, dout);
  zero_kernel<<<KCODES / 256, 256, 0, stream>>>(dout);
  pass1_mfma<<<dim3(NCHUNK, NTOK / 128), 256, 0, stream>>>(x, cb, dout);
  merge_rows<<<NTOK / 256, 256, 0, stream>>>(dout);
  refine<<<NTOK, 64, 0, stream>>>(x, cb, dout);
  col_mfma<<<dim3(NCHUNK, NTOK / 128), 256, 0, stream>>>(x, cb, dout);
  finalize<<<1, 256, 0, stream>>>(dout);
  gather_kernel<<<NTOK, 128, 0, stream>>>(x, cb, dout);
}

// Round 7
// 663.550 us; speedup vs baseline: 2.7768x; 1.4286x over previous
//
#include <hip/hip_runtime.h>
#include <math.h>

#define NTOK 8192
#define KCODES 8192
#define DDIM 512
#define QELEMS (NTOK * DDIM)

// ---------------- fallback (round-6) chunking / offsets ---------------------
#define NCHUNK 8
#define CPC (KCODES / NCHUNK)   // 1024
#define LDK 40

constexpr size_t S_PART  = 0;                    // 8192 tok * 8 chunks * 8 f
constexpr size_t S_XSQ   = 524288;
constexpr size_t S_CSQ   = S_XSQ + NTOK;
constexpr size_t S_LSE   = S_CSQ + KCODES;
constexpr size_t S_PLOGP = S_LSE + NTOK;
constexpr size_t S_D2    = S_PLOGP + NTOK;
constexpr size_t S_AVG   = S_D2 + NTOK;
constexpr size_t S_I1    = S_AVG + KCODES;
constexpr size_t S_I2    = S_I1 + NTOK;

// ---------------- fast-path chunking / offsets ------------------------------
#define NCHUNK_F 16
#define CPC_F (KCODES / NCHUNK_F)  // 512

constexpr size_t FS_PART  = 0;                        // 8192*16*8 = 1,048,576
constexpr size_t FS_XSQ   = 1048576;
constexpr size_t FS_CSQ   = FS_XSQ + NTOK;
constexpr size_t FS_LSE   = FS_CSQ + KCODES;
constexpr size_t FS_PLOGP = FS_LSE + NTOK;
constexpr size_t FS_D2    = FS_PLOGP + NTOK;
constexpr size_t FS_AVG   = FS_D2 + NTOK;
constexpr size_t FS_I1    = FS_AVG + KCODES;
constexpr size_t FS_I2    = FS_I1 + NTOK;

// ws layout (shorts): [0]=XH [1]=XL [2]=CBH [3]=CBL, each QELEMS shorts,
// tiled: idx(tile,kt,g,r,e) = ((tile*16+kt)*4+g)*1024 + r*8 + e
constexpr size_t WS_NEED_BYTES = 4ull * (size_t)QELEMS * 2ull;  // 33,554,432

typedef __attribute__((ext_vector_type(8))) short bf16x8;
typedef __attribute__((ext_vector_type(4))) float f32x4;

__device__ __forceinline__ bool better(float v, int i, float v2, int i2) {
  return v > v2 || (v == v2 && i < i2);
}

// fp32 -> (hi, lo) bf16 pair by truncation; hi+lo carries ~17 mantissa bits
__device__ __forceinline__ void cvt_hilo(float f, unsigned& h, unsigned& l) {
  const unsigned u = __float_as_uint(f);
  h = u >> 16;
  const float lf = f - __uint_as_float(u & 0xFFFF0000u);
  l = __float_as_uint(lf) >> 16;
}

__device__ __forceinline__ void gll16(const unsigned short* g, const short* l) {
  __builtin_amdgcn_global_load_lds(
      (const __attribute__((address_space(1))) unsigned int*)g,
      (__attribute__((address_space(3))) unsigned int*)l, 16, 0, 0);
}

// ---------------- squared norms (shared; offsets parameterized) -------------
__global__ __launch_bounds__(64) void sq_kernel(const float* __restrict__ x,
                                                const float* __restrict__ cb,
                                                float* __restrict__ dout,
                                                size_t offXsq, size_t offCsq) {
  const int row = blockIdx.x;  // 0..8191 codes, 8192..16383 tokens
  const int lane = threadIdx.x;
  const float* src = (row < KCODES) ? (cb + (size_t)row * DDIM)
                                    : (x + (size_t)(row - KCODES) * DDIM);
  float4 v0 = reinterpret_cast<const float4*>(src)[lane];
  float4 v1 = reinterpret_cast<const float4*>(src)[lane + 64];
  float s = v0.x*v0.x + v0.y*v0.y + v0.z*v0.z + v0.w*v0.w
          + v1.x*v1.x + v1.y*v1.y + v1.z*v1.z + v1.w*v1.w;
  #pragma unroll
  for (int o = 32; o; o >>= 1) s += __shfl_down(s, o);
  if (lane == 0) {
    if (row < KCODES) dout[offCsq + row] = s;
    else              dout[offXsq + (row - KCODES)] = s;
  }
}

__global__ void zero_kernel(float* __restrict__ dout, size_t offAvg) {
  dout[offAvg + blockIdx.x * 256 + threadIdx.x] = 0.f;
}

// ---------------- one-time fp32 -> tiled bf16 hi/lo conversion --------------
__global__ __launch_bounds__(256) void cvt_kernel(const float* __restrict__ x,
                                                  const float* __restrict__ cb,
                                                  unsigned short* __restrict__ ws) {
  const size_t fid = (size_t)blockIdx.x * 256 + threadIdx.x;  // float4 id
  const size_t half = (size_t)QELEMS / 4;                     // 1,048,576
  const bool isX = fid < half;
  const float* src = isX ? x : cb;
  unsigned short* dh = ws + (isX ? 0 : (size_t)2 * QELEMS);
  unsigned short* dl = dh + QELEMS;
  const size_t f = isX ? fid : fid - half;
  const size_t e0 = f * 4;
  const int row = (int)(e0 >> 9);
  const int k = (int)(e0 & 511);
  const int tile = row >> 7, r = row & 127;
  const int kt = k >> 5, gg = (k >> 3) & 3, e = k & 7;  // e in {0,4}
  const float4 v = *reinterpret_cast<const float4*>(src + e0);
  unsigned h0, h1, h2, h3, l0, l1, l2, l3;
  cvt_hilo(v.x, h0, l0); cvt_hilo(v.y, h1, l1);
  cvt_hilo(v.z, h2, l2); cvt_hilo(v.w, h3, l3);
  uint2 hp, lp;
  hp.x = h0 | (h1 << 16); hp.y = h2 | (h3 << 16);
  lp.x = l0 | (l1 << 16); lp.y = l2 | (l3 << 16);
  const size_t dst = (((size_t)tile * 16 + kt) * 4 + gg) * 1024 + (size_t)r * 8 + e;
  *reinterpret_cast<uint2*>(dh + dst) = hp;
  *reinterpret_cast<uint2*>(dl + dst) = lp;
}

// =========================================================================
// FAST PATH: global_load_lds staged MFMA GEMMs (no conversion in-loop)
// =========================================================================

#define MFMA_KSTEP_F                                                          \
  {                                                                           \
    bf16x8 a_h[4], a_l[4];                                                    \
    _Pragma("unroll")                                                         \
    for (int fi = 0; fi < 4; ++fi) {                                          \
      const int ra = (wr * 64 + fi * 16 + lx) * 8 + kg * 1024;                \
      a_h[fi] = *reinterpret_cast<const bf16x8*>(&lds4[0][ra]);               \
      a_l[fi] = *reinterpret_cast<const bf16x8*>(&lds4[1][ra]);               \
    }                                                                         \
    _Pragma("unroll")                                                         \
    for (int fj = 0; fj < 4; ++fj) {                                          \
      const int rb = (wc * 64 + fj * 16 + lx) * 8 + kg * 1024;                \
      const bf16x8 b_h = *reinterpret_cast<const bf16x8*>(&lds4[2][rb]);      \
      const bf16x8 b_l = *reinterpret_cast<const bf16x8*>(&lds4[3][rb]);      \
      _Pragma("unroll")                                                       \
      for (int fi = 0; fi < 4; ++fi) {                                        \
        acc[fi][fj] = __builtin_amdgcn_mfma_f32_16x16x32_bf16(a_h[fi], b_h, acc[fi][fj], 0, 0, 0); \
        acc[fi][fj] = __builtin_amdgcn_mfma_f32_16x16x32_bf16(a_l[fi], b_h, acc[fi][fj], 0, 0, 0); \
        acc[fi][fj] = __builtin_amdgcn_mfma_f32_16x16x32_bf16(a_h[fi], b_l, acc[fi][fj], 0, 0, 0); \
      }                                                                       \
    }                                                                         \
  }

#define STAGE_F(kt_)                                                          \
  {                                                                           \
    const unsigned short* p = gb + (((size_t)tile * 16 + (kt_)) * 4096) + l * 8; \
    const short* lb = &lds4[w][0];                                            \
    _Pragma("unroll")                                                         \
    for (int s8 = 0; s8 < 8; ++s8) gll16(p + s8 * 512, lb + s8 * 512);        \
  }

// ---------------- fast pass 1: GEMM + fused online row stats ----------------
__global__ __launch_bounds__(256, 3) void pass1f(const unsigned short* __restrict__ ws,
                                                 float* __restrict__ dout) {
  __shared__ short lds4[4][4096];      // Ah, Al, Bh, Bl  (tiled [g][128][8])
  __shared__ float stats[2][128][6];   // [wc][row]{m, z, s1, v2, i1, i2}
  const int tid = threadIdx.x;
  const int l = tid & 63;
  const int w = tid >> 6;
  const int wr = w >> 1, wc = w & 1;
  const int kg = l >> 4, lx = l & 15;
  const int m0 = blockIdx.y * 128;
  const int atile = blockIdx.y;
  const int chunk = blockIdx.x;

  if (tid < 128) {
    #pragma unroll
    for (int q = 0; q < 2; ++q) {
      stats[q][tid][0] = -1e30f; stats[q][tid][1] = 0.f; stats[q][tid][2] = 0.f;
      stats[q][tid][3] = -1e30f;
      stats[q][tid][4] = __int_as_float(0x7fffffff);
      stats[q][tid][5] = __int_as_float(0x7fffffff);
    }
  }

  float xs[16];
  #pragma unroll
  for (int fi = 0; fi < 4; ++fi)
    #pragma unroll
    for (int v = 0; v < 4; ++v)
      xs[fi * 4 + v] = dout[FS_XSQ + m0 + wr * 64 + fi * 16 + kg * 4 + v];

  const unsigned short* gb = ws + (size_t)w * (size_t)QELEMS;

  for (int st = 0; st < CPC_F / 128; ++st) {
    const int n0 = chunk * CPC_F + st * 128;
    const int tile = (w < 2) ? atile : (n0 >> 7);
    f32x4 acc[4][4];
    #pragma unroll
    for (int fi = 0; fi < 4; ++fi)
      #pragma unroll
      for (int fj = 0; fj < 4; ++fj)
        acc[fi][fj] = (f32x4){0.f, 0.f, 0.f, 0.f};

    for (int kt = 0; kt < DDIM / 32; ++kt) {
      __syncthreads();
      STAGE_F(kt);
      __syncthreads();
      MFMA_KSTEP_F;
    }

    // fused epilogue: per-row online softmax stats + top-2
    const int colbase = n0 + wc * 64 + lx;
    float cs[4];
    #pragma unroll
    for (int fj = 0; fj < 4; ++fj) cs[fj] = dout[FS_CSQ + colbase + fj * 16];

    #pragma unroll
    for (int fi = 0; fi < 4; ++fi) {
      #pragma unroll
      for (int v = 0; v < 4; ++v) {
        const float xsv = xs[fi * 4 + v];
        float fv[4];
        #pragma unroll
        for (int fj = 0; fj < 4; ++fj) {
          const float d2 = fmaxf(fmaf(-2.f, acc[fi][fj][v], xsv) + cs[fj], 0.f);
          fv[fj] = -100.f * sqrtf(d2);
        }
        float v1 = fv[0], v2 = -1e30f;
        int i1 = colbase, i2 = 0x7fffffff;
        #pragma unroll
        for (int fj = 1; fj < 4; ++fj) {
          const int c = colbase + fj * 16;
          if (better(fv[fj], c, v1, i1)) { v2 = v1; i2 = i1; v1 = fv[fj]; i1 = c; }
          else if (better(fv[fj], c, v2, i2)) { v2 = fv[fj]; i2 = c; }
        }
        #pragma unroll
        for (int mask = 1; mask < 16; mask <<= 1) {
          const float ov1 = __shfl_xor(v1, mask);
          const float ov2 = __shfl_xor(v2, mask);
          const int oi1 = __shfl_xor(i1, mask);
          const int oi2 = __shfl_xor(i2, mask);
          float n1, n2; int ni1, ni2;
          if (better(ov1, oi1, v1, i1)) {
            n1 = ov1; ni1 = oi1;
            if (better(v1, i1, ov2, oi2)) { n2 = v1; ni2 = i1; } else { n2 = ov2; ni2 = oi2; }
          } else {
            n1 = v1; ni1 = i1;
            if (better(ov1, oi1, v2, i2)) { n2 = ov1; ni2 = oi1; } else { n2 = v2; ni2 = i2; }
          }
          v1 = n1; i1 = ni1; v2 = n2; i2 = ni2;
        }
        float z = 0.f, s = 0.f;
        #pragma unroll
        for (int fj = 0; fj < 4; ++fj) {
          const float ge = fv[fj] - v1;
          const float e = __expf(ge);
          z += e; s = fmaf(e, ge, s);
        }
        #pragma unroll
        for (int mask = 1; mask < 16; mask <<= 1) {
          z += __shfl_xor(z, mask);
          s += __shfl_xor(s, mask);
        }
        if (lx == 0) {
          const int r = wr * 64 + fi * 16 + kg * 4 + v;
          float* st_ = &stats[wc][r][0];
          const float ov1 = st_[0], oz = st_[1], os = st_[2], ov2 = st_[3];
          const int oi1 = __float_as_int(st_[4]), oi2 = __float_as_int(st_[5]);
          const float M = fmaxf(v1, ov1);
          const float ea = __expf(v1 - M), eb = __expf(ov1 - M);
          st_[1] = ea * z + eb * oz;
          st_[2] = ea * (s + (v1 - M) * z) + eb * (os + (ov1 - M) * oz);
          float n1, n2; int ni1, ni2;
          if (better(ov1, oi1, v1, i1)) {
            n1 = ov1; ni1 = oi1;
            if (better(v1, i1, ov2, oi2)) { n2 = v1; ni2 = i1; } else { n2 = ov2; ni2 = oi2; }
          } else {
            n1 = v1; ni1 = i1;
            if (better(ov1, oi1, v2, i2)) { n2 = ov1; ni2 = oi1; } else { n2 = v2; ni2 = i2; }
          }
          st_[0] = n1; st_[3] = n2;
          st_[4] = __int_as_float(ni1);
          st_[5] = __int_as_float(ni2);
        }
      }
    }
  }

  __syncthreads();
  if (tid < 128) {
    float v1 = stats[0][tid][0], z = stats[0][tid][1], s = stats[0][tid][2], v2 = stats[0][tid][3];
    int i1 = __float_as_int(stats[0][tid][4]), i2 = __float_as_int(stats[0][tid][5]);
    const float ov1 = stats[1][tid][0], oz = stats[1][tid][1];
    const float os = stats[1][tid][2], ov2 = stats[1][tid][3];
    const int oi1 = __float_as_int(stats[1][tid][4]), oi2 = __float_as_int(stats[1][tid][5]);
    const float M = fmaxf(v1, ov1);
    const float ea = __expf(v1 - M), eb = __expf(ov1 - M);
    const float nz = ea * z + eb * oz;
    const float ns = ea * (s + (v1 - M) * z) + eb * (os + (ov1 - M) * oz);
    float n1, n2; int ni1, ni2;
    if (better(ov1, oi1, v1, i1)) {
      n1 = ov1; ni1 = oi1;
      if (better(v1, i1, ov2, oi2)) { n2 = v1; ni2 = i1; } else { n2 = ov2; ni2 = oi2; }
    } else {
      n1 = v1; ni1 = i1;
      if (better(ov1, oi1, v2, i2)) { n2 = ov1; ni2 = oi1; } else { n2 = v2; ni2 = i2; }
    }
    float* p = dout + FS_PART + ((size_t)(m0 + tid) * NCHUNK_F + chunk) * 8;
    p[0] = n1; p[1] = nz; p[2] = ns; p[3] = n2;
    p[4] = __int_as_float(ni1); p[5] = __int_as_float(ni2);
  }
}

// ---------------- fast pass 2: GEMM + avg_probs column sums -----------------
__global__ __launch_bounds__(256, 3) void colf(const unsigned short* __restrict__ ws,
                                               float* __restrict__ dout) {
  __shared__ short lds4[4][4096];
  __shared__ float red[4][64];
  const int tid = threadIdx.x;
  const int l = tid & 63;
  const int w = tid >> 6;
  const int wr = w >> 1, wc = w & 1;
  const int kg = l >> 4, lx = l & 15;
  const int m0 = blockIdx.y * 128;
  const int atile = blockIdx.y;
  const int chunk = blockIdx.x;

  float xs[16], lse[16];
  #pragma unroll
  for (int fi = 0; fi < 4; ++fi)
    #pragma unroll
    for (int v = 0; v < 4; ++v) {
      const int r = m0 + wr * 64 + fi * 16 + kg * 4 + v;
      xs[fi * 4 + v] = dout[FS_XSQ + r];
      lse[fi * 4 + v] = dout[FS_LSE + r];
    }

  const unsigned short* gb = ws + (size_t)w * (size_t)QELEMS;

  for (int st = 0; st < CPC_F / 128; ++st) {
    const int n0 = chunk * CPC_F + st * 128;
    const int tile = (w < 2) ? atile : (n0 >> 7);
    f32x4 acc[4][4];
    #pragma unroll
    for (int fi = 0; fi < 4; ++fi)
      #pragma unroll
      for (int fj = 0; fj < 4; ++fj)
        acc[fi][fj] = (f32x4){0.f, 0.f, 0.f, 0.f};

    for (int kt = 0; kt < DDIM / 32; ++kt) {
      __syncthreads();
      STAGE_F(kt);
      __syncthreads();
      MFMA_KSTEP_F;
    }

    const int colbase = n0 + wc * 64 + lx;
    float cs[4];
    #pragma unroll
    for (int fj = 0; fj < 4; ++fj) cs[fj] = dout[FS_CSQ + colbase + fj * 16];

    float colsum[4] = {0.f, 0.f, 0.f, 0.f};
    #pragma unroll
    for (int fi = 0; fi < 4; ++fi) {
      #pragma unroll
      for (int v = 0; v < 4; ++v) {
        const float xsv = xs[fi * 4 + v];
        const float lsev = lse[fi * 4 + v];
        #pragma unroll
        for (int fj = 0; fj < 4; ++fj) {
          const float d2 = fmaxf(fmaf(-2.f, acc[fi][fj][v], xsv) + cs[fj], 0.f);
          const float f = -100.f * sqrtf(d2);
          colsum[fj] += __expf(f - lsev);
        }
      }
    }
    #pragma unroll
    for (int fj = 0; fj < 4; ++fj) {
      colsum[fj] += __shfl_xor(colsum[fj], 16);
      colsum[fj] += __shfl_xor(colsum[fj], 32);
    }
    __syncthreads();
    if (kg == 0) {
      #pragma unroll
      for (int fj = 0; fj < 4; ++fj) red[w][fj * 16 + lx] = colsum[fj];
    }
    __syncthreads();
    if (tid < 128) {
      const int wcc = tid >> 6, c = tid & 63;
      atomicAdd(&dout[FS_AVG + n0 + tid], red[wcc][c] + red[wcc + 2][c]);
    }
  }
}

// =========================================================================
// FALLBACK (round-6 kernels, verbatim structure)
// =========================================================================

#define STAGE_TILES(kt_)                                                      \
  {                                                                           \
    const int kb = (kt_) * 32 + sc;                                           \
    _Pragma("unroll")                                                         \
    for (int rep = 0; rep < 4; ++rep) {                                       \
      const int row = sr + rep * 32;                                          \
      const float4 av = *reinterpret_cast<const float4*>(                     \
          x + (size_t)(m0 + row) * DDIM + kb);                                \
      const float4 bv = *reinterpret_cast<const float4*>(                     \
          cb + (size_t)(n0 + row) * DDIM + kb);                               \
      unsigned h0, h1, h2, h3, l0, l1, l2, l3;                                \
      uint2 t;                                                                \
      cvt_hilo(av.x, h0, l0); cvt_hilo(av.y, h1, l1);                         \
      cvt_hilo(av.z, h2, l2); cvt_hilo(av.w, h3, l3);                         \
      t.x = h0 | (h1 << 16); t.y = h2 | (h3 << 16);                           \
      *reinterpret_cast<uint2*>(&Ah[row][sc]) = t;                            \
      t.x = l0 | (l1 << 16); t.y = l2 | (l3 << 16);                           \
      *reinterpret_cast<uint2*>(&Al[row][sc]) = t;                            \
      cvt_hilo(bv.x, h0, l0); cvt_hilo(bv.y, h1, l1);                         \
      cvt_hilo(bv.z, h2, l2); cvt_hilo(bv.w, h3, l3);                         \
      t.x = h0 | (h1 << 16); t.y = h2 | (h3 << 16);                           \
      *reinterpret_cast<uint2*>(&Bh[row][sc]) = t;                            \
      t.x = l0 | (l1 << 16); t.y = l2 | (l3 << 16);                           \
      *reinterpret_cast<uint2*>(&Bl[row][sc]) = t;                            \
    }                                                                         \
  }

#define MFMA_KSTEP                                                            \
  {                                                                           \
    bf16x8 a_h[4], a_l[4];                                                    \
    _Pragma("unroll")                                                         \
    for (int fi = 0; fi < 4; ++fi) {                                          \
      a_h[fi] = *reinterpret_cast<const bf16x8*>(&Ah[ar + fi * 16][koff]);    \
      a_l[fi] = *reinterpret_cast<const bf16x8*>(&Al[ar + fi * 16][koff]);    \
    }                                                                         \
    _Pragma("unroll")                                                         \
    for (int fj = 0; fj < 4; ++fj) {                                          \
      const bf16x8 b_h = *reinterpret_cast<const bf16x8*>(&Bh[br + fj * 16][koff]); \
      const bf16x8 b_l = *reinterpret_cast<const bf16x8*>(&Bl[br + fj * 16][koff]); \
      _Pragma("unroll")                                                       \
      for (int fi = 0; fi < 4; ++fi) {                                        \
        acc[fi][fj] = __builtin_amdgcn_mfma_f32_16x16x32_bf16(a_h[fi], b_h, acc[fi][fj], 0, 0, 0); \
        acc[fi][fj] = __builtin_amdgcn_mfma_f32_16x16x32_bf16(a_l[fi], b_h, acc[fi][fj], 0, 0, 0); \
        acc[fi][fj] = __builtin_amdgcn_mfma_f32_16x16x32_bf16(a_h[fi], b_l, acc[fi][fj], 0, 0, 0); \
      }                                                                       \
    }                                                                         \
  }

__global__ __launch_bounds__(256) void pass1_mfma(const float* __restrict__ x,
                                                  const float* __restrict__ cb,
                                                  float* __restrict__ dout) {
  __shared__ short Ah[128][LDK], Al[128][LDK], Bh[128][LDK], Bl[128][LDK];
  __shared__ float stats[2][128][6];
  const int tid = threadIdx.x;
  const int l = tid & 63;
  const int w = tid >> 6;
  const int wr = w >> 1, wc = w & 1;
  const int g = l >> 4, lx = l & 15;
  const int ar = wr * 64 + lx;
  const int br = wc * 64 + lx;
  const int koff = g * 8;
  const int sr = tid >> 3;
  const int sc = (tid & 7) * 4;
  const int m0 = blockIdx.y * 128;
  const int chunk = blockIdx.x;

  if (tid < 128) {
    #pragma unroll
    for (int q = 0; q < 2; ++q) {
      stats[q][tid][0] = -1e30f; stats[q][tid][1] = 0.f; stats[q][tid][2] = 0.f;
      stats[q][tid][3] = -1e30f;
      stats[q][tid][4] = __int_as_float(0x7fffffff);
      stats[q][tid][5] = __int_as_float(0x7fffffff);
    }
  }

  float xs[16];
  #pragma unroll
  for (int fi = 0; fi < 4; ++fi)
    #pragma unroll
    for (int v = 0; v < 4; ++v)
      xs[fi * 4 + v] = dout[S_XSQ + m0 + wr * 64 + fi * 16 + g * 4 + v];

  for (int st = 0; st < CPC / 128; ++st) {
    const int n0 = chunk * CPC + st * 128;
    f32x4 acc[4][4];
    #pragma unroll
    for (int fi = 0; fi < 4; ++fi)
      #pragma unroll
      for (int fj = 0; fj < 4; ++fj)
        acc[fi][fj] = (f32x4){0.f, 0.f, 0.f, 0.f};

    for (int kt = 0; kt < DDIM / 32; ++kt) {
      __syncthreads();
      STAGE_TILES(kt);
      __syncthreads();
      MFMA_KSTEP;
    }

    const int colbase = n0 + wc * 64 + lx;
    float cs[4];
    #pragma unroll
    for (int fj = 0; fj < 4; ++fj) cs[fj] = dout[S_CSQ + colbase + fj * 16];

    #pragma unroll
    for (int fi = 0; fi < 4; ++fi) {
      #pragma unroll
      for (int v = 0; v < 4; ++v) {
        const float xsv = xs[fi * 4 + v];
        float fv[4];
        #pragma unroll
        for (int fj = 0; fj < 4; ++fj) {
          const float d2 = fmaxf(fmaf(-2.f, acc[fi][fj][v], xsv) + cs[fj], 0.f);
          fv[fj] = -100.f * sqrtf(d2);
        }
        float v1 = fv[0], v2 = -1e30f;
        int i1 = colbase, i2 = 0x7fffffff;
        #pragma unroll
        for (int fj = 1; fj < 4; ++fj) {
          const int c = colbase + fj * 16;
          if (better(fv[fj], c, v1, i1)) { v2 = v1; i2 = i1; v1 = fv[fj]; i1 = c; }
          else if (better(fv[fj], c, v2, i2)) { v2 = fv[fj]; i2 = c; }
        }
        #pragma unroll
        for (int mask = 1; mask < 16; mask <<= 1) {
          const float ov1 = __shfl_xor(v1, mask);
          const float ov2 = __shfl_xor(v2, mask);
          const int oi1 = __shfl_xor(i1, mask);
          const int oi2 = __shfl_xor(i2, mask);
          float n1, n2; int ni1, ni2;
          if (better(ov1, oi1, v1, i1)) {
            n1 = ov1; ni1 = oi1;
            if (better(v1, i1, ov2, oi2)) { n2 = v1; ni2 = i1; } else { n2 = ov2; ni2 = oi2; }
          } else {
            n1 = v1; ni1 = i1;
            if (better(ov1, oi1, v2, i2)) { n2 = ov1; ni2 = oi1; } else { n2 = v2; ni2 = i2; }
          }
          v1 = n1; i1 = ni1; v2 = n2; i2 = ni2;
        }
        float z = 0.f, s = 0.f;
        #pragma unroll
        for (int fj = 0; fj < 4; ++fj) {
          const float ge = fv[fj] - v1;
          const float e = __expf(ge);
          z += e; s = fmaf(e, ge, s);
        }
        #pragma unroll
        for (int mask = 1; mask < 16; mask <<= 1) {
          z += __shfl_xor(z, mask);
          s += __shfl_xor(s, mask);
        }
        if (lx == 0) {
          const int r = wr * 64 + fi * 16 + g * 4 + v;
          float* st_ = &stats[wc][r][0];
          const float ov1 = st_[0], oz = st_[1], os = st_[2], ov2 = st_[3];
          const int oi1 = __float_as_int(st_[4]), oi2 = __float_as_int(st_[5]);
          const float M = fmaxf(v1, ov1);
          const float ea = __expf(v1 - M), eb = __expf(ov1 - M);
          st_[1] = ea * z + eb * oz;
          st_[2] = ea * (s + (v1 - M) * z) + eb * (os + (ov1 - M) * oz);
          float n1, n2; int ni1, ni2;
          if (better(ov1, oi1, v1, i1)) {
            n1 = ov1; ni1 = oi1;
            if (better(v1, i1, ov2, oi2)) { n2 = v1; ni2 = i1; } else { n2 = ov2; ni2 = oi2; }
          } else {
            n1 = v1; ni1 = i1;
            if (better(ov1, oi1, v2, i2)) { n2 = ov1; ni2 = oi1; } else { n2 = v2; ni2 = i2; }
          }
          st_[0] = n1; st_[3] = n2;
          st_[4] = __int_as_float(ni1);
          st_[5] = __int_as_float(ni2);
        }
      }
    }
  }

  __syncthreads();
  if (tid < 128) {
    float v1 = stats[0][tid][0], z = stats[0][tid][1], s = stats[0][tid][2], v2 = stats[0][tid][3];
    int i1 = __float_as_int(stats[0][tid][4]), i2 = __float_as_int(stats[0][tid][5]);
    const float ov1 = stats[1][tid][0], oz = stats[1][tid][1];
    const float os = stats[1][tid][2], ov2 = stats[1][tid][3];
    const int oi1 = __float_as_int(stats[1][tid][4]), oi2 = __float_as_int(stats[1][tid][5]);
    const float M = fmaxf(v1, ov1);
    const float ea = __expf(v1 - M), eb = __expf(ov1 - M);
    const float nz = ea * z + eb * oz;
    const float ns = ea * (s + (v1 - M) * z) + eb * (os + (ov1 - M) * oz);
    float n1, n2; int ni1, ni2;
    if (better(ov1, oi1, v1, i1)) {
      n1 = ov1; ni1 = oi1;
      if (better(v1, i1, ov2, oi2)) { n2 = v1; ni2 = i1; } else { n2 = ov2; ni2 = oi2; }
    } else {
      n1 = v1; ni1 = i1;
      if (better(ov1, oi1, v2, i2)) { n2 = ov1; ni2 = oi1; } else { n2 = v2; ni2 = i2; }
    }
    float* p = dout + S_PART + ((size_t)(m0 + tid) * NCHUNK + chunk) * 8;
    p[0] = n1; p[1] = nz; p[2] = ns; p[3] = n2;
    p[4] = __int_as_float(ni1); p[5] = __int_as_float(ni2);
  }
}

__global__ __launch_bounds__(256) void col_mfma(const float* __restrict__ x,
                                                const float* __restrict__ cb,
                                                float* __restrict__ dout) {
  __shared__ short Ah[128][LDK], Al[128][LDK], Bh[128][LDK], Bl[128][LDK];
  __shared__ float red[4][64];
  const int tid = threadIdx.x;
  const int l = tid & 63;
  const int w = tid >> 6;
  const int wr = w >> 1, wc = w & 1;
  const int g = l >> 4, lx = l & 15;
  const int ar = wr * 64 + lx;
  const int br = wc * 64 + lx;
  const int koff = g * 8;
  const int sr = tid >> 3;
  const int sc = (tid & 7) * 4;
  const int m0 = blockIdx.y * 128;
  const int chunk = blockIdx.x;

  float xs[16], lse[16];
  #pragma unroll
  for (int fi = 0; fi < 4; ++fi)
    #pragma unroll
    for (int v = 0; v < 4; ++v) {
      const int r = m0 + wr * 64 + fi * 16 + g * 4 + v;
      xs[fi * 4 + v] = dout[S_XSQ + r];
      lse[fi * 4 + v] = dout[S_LSE + r];
    }

  for (int st = 0; st < CPC / 128; ++st) {
    const int n0 = chunk * CPC + st * 128;
    f32x4 acc[4][4];
    #pragma unroll
    for (int fi = 0; fi < 4; ++fi)
      #pragma unroll
      for (int fj = 0; fj < 4; ++fj)
        acc[fi][fj] = (f32x4){0.f, 0.f, 0.f, 0.f};

    for (int kt = 0; kt < DDIM / 32; ++kt) {
      __syncthreads();
      STAGE_TILES(kt);
      __syncthreads();
      MFMA_KSTEP;
    }

    const int colbase = n0 + wc * 64 + lx;
    float cs[4];
    #pragma unroll
    for (int fj = 0; fj < 4; ++fj) cs[fj] = dout[S_CSQ + colbase + fj * 16];

    float colsum[4] = {0.f, 0.f, 0.f, 0.f};
    #pragma unroll
    for (int fi = 0; fi < 4; ++fi) {
      #pragma unroll
      for (int v = 0; v < 4; ++v) {
        const float xsv = xs[fi * 4 + v];
        const float lsev = lse[fi * 4 + v];
        #pragma unroll
        for (int fj = 0; fj < 4; ++fj) {
          const float d2 = fmaxf(fmaf(-2.f, acc[fi][fj][v], xsv) + cs[fj], 0.f);
          const float f = -100.f * sqrtf(d2);
          colsum[fj] += __expf(f - lsev);
        }
      }
    }
    #pragma unroll
    for (int fj = 0; fj < 4; ++fj) {
      colsum[fj] += __shfl_xor(colsum[fj], 16);
      colsum[fj] += __shfl_xor(colsum[fj], 32);
    }
    __syncthreads();
    if (g == 0) {
      #pragma unroll
      for (int fj = 0; fj < 4; ++fj) red[w][fj * 16 + lx] = colsum[fj];
    }
    __syncthreads();
    if (tid < 128) {
      const int wcc = tid >> 6, c = tid & 63;
      atomicAdd(&dout[S_AVG + n0 + tid], red[wcc][c] + red[wcc + 2][c]);
    }
  }
}

// ---------------- shared small kernels (offset-parameterized) ---------------
__global__ __launch_bounds__(256) void merge_rows(float* __restrict__ dout,
                                                  size_t offPart, int nchunk,
                                                  size_t offLse, size_t offPlogp,
                                                  size_t offI1, size_t offI2) {
  const int t = blockIdx.x * 256 + threadIdx.x;
  float v1 = -1e30f, v2 = -1e30f, z = 0.f, s1 = 0.f;
  int i1 = 0x7fffffff, i2 = 0x7fffffff;
  for (int c = 0; c < nchunk; ++c) {
    const float* p = dout + offPart + ((size_t)t * nchunk + c) * 8;
    const float ov1 = p[0], oz = p[1], os1 = p[2], ov2 = p[3];
    const int oi1 = __float_as_int(p[4]), oi2 = __float_as_int(p[5]);
    const float M = fmaxf(v1, ov1);
    const float a = __expf(v1 - M);
    const float b = __expf(ov1 - M);
    s1 = a * (s1 + (v1 - M) * z) + b * (os1 + (ov1 - M) * oz);
    z  = a * z + b * oz;
    float n1, n2; int ni1, ni2;
    if (better(ov1, oi1, v1, i1)) {
      n1 = ov1; ni1 = oi1;
      if (better(v1, i1, ov2, oi2)) { n2 = v1; ni2 = i1; }
      else { n2 = ov2; ni2 = oi2; }
    } else {
      n1 = v1; ni1 = i1;
      if (better(ov1, oi1, v2, i2)) { n2 = ov1; ni2 = oi1; }
      else { n2 = v2; ni2 = i2; }
    }
    v1 = n1; i1 = ni1; v2 = n2; i2 = ni2;
  }
  const float lnZ = logf(z);
  dout[offLse + t] = v1 + lnZ;
  dout[offPlogp + t] = s1 / z - lnZ;
  reinterpret_cast<int*>(dout)[offI1 + t] = i1;
  reinterpret_cast<int*>(dout)[offI2 + t] = i2;
}

__global__ __launch_bounds__(64) void refine(const float* __restrict__ x,
                                             const float* __restrict__ cb,
                                             float* __restrict__ dout,
                                             size_t offI1, size_t offI2,
                                             size_t offD2) {
  const int t = blockIdx.x;
  const int lane = threadIdx.x;
  const int i1 = reinterpret_cast<const int*>(dout)[offI1 + t];
  const int i2 = reinterpret_cast<const int*>(dout)[offI2 + t];
  const float* xt = x + (size_t)t * DDIM;
  const float* c1 = cb + (size_t)i1 * DDIM;
  const float* c2 = cb + (size_t)i2 * DDIM;
  double d1 = 0.0, d2 = 0.0;
  #pragma unroll
  for (int j = 0; j < DDIM / 64; ++j) {
    const int d = j * 64 + lane;
    const double xv = (double)xt[d];
    const double u = xv - (double)c1[d];
    const double w = xv - (double)c2[d];
    d1 += u * u;
    d2 += w * w;
  }
  #pragma unroll
  for (int o = 32; o; o >>= 1) { d1 += __shfl_down(d1, o); d2 += __shfl_down(d2, o); }
  if (lane == 0) {
    const bool pick2 = (d2 < d1) || (d2 == d1 && i2 < i1);
    dout[offD2 + t] = (float)(pick2 ? d2 : d1);
    dout[(size_t)QELEMS + 4 + t] = (float)(pick2 ? i2 : i1);
  }
}

__global__ __launch_bounds__(256) void finalize(float* __restrict__ dout,
                                                size_t offAvg, size_t offPlogp,
                                                size_t offD2) {
  const int tid = threadIdx.x;
  float ent = 0.f, sp = 0.f, sd = 0.f;
  for (int j = 0; j < KCODES / 256; ++j) {
    const float a = dout[offAvg + j * 256 + tid] * (1.0f / (float)NTOK);
    ent -= a * logf(a + 1e-8f);
    sp += dout[offPlogp + j * 256 + tid];
    sd += dout[offD2 + j * 256 + tid];
  }
  __shared__ float se[256], sP[256], sD[256];
  se[tid] = ent; sP[tid] = sp; sD[tid] = sd;
  __syncthreads();
  for (int s = 128; s > 0; s >>= 1) {
    if (tid < s) { se[tid] += se[tid + s]; sP[tid] += sP[tid + s]; sD[tid] += sD[tid + s]; }
    __syncthreads();
  }
  if (tid == 0) {
    const float avg_entropy = se[0];
    const float sample_entropy = -sP[0] / (float)NTOK;
    const float entropy_loss = (sample_entropy - avg_entropy) * 0.1f;
    const float mse = sD[0] / (float)QELEMS;
    const float commit = 0.5f * mse * 0.25f;
    const float cbl = 0.5f * mse;
    dout[QELEMS + 0] = cbl + commit + entropy_loss;
    dout[QELEMS + 1] = commit;
    dout[QELEMS + 2] = cbl;
    dout[QELEMS + 3] = entropy_loss;
  }
}

__global__ __launch_bounds__(128) void gather_kernel(const float* __restrict__ x,
                                                     const float* __restrict__ cb,
                                                     float* __restrict__ dout) {
  const int t = blockIdx.x;
  const int tid = threadIdx.x;
  const int idx = (int)dout[(size_t)QELEMS + 4 + t];
  const float4 cv = reinterpret_cast<const float4*>(cb + (size_t)idx * DDIM)[tid];
  reinterpret_cast<float4*>(dout + (size_t)t * DDIM)[tid] = cv;
}

extern "C" void kernel_launch(void* const* d_in, const int* in_sizes, int n_in,
                              void* d_out, int out_size, void* d_ws, size_t ws_size,
                              hipStream_t stream) {
  const float* x = (const float*)d_in[0];    // (4,2048,512)
  const float* cb = (const float*)d_in[1];   // (8192,512)
  float* dout = (float*)d_out;

  if (ws_size >= WS_NEED_BYTES) {
    unsigned short* ws = (unsigned short*)d_ws;
    sq_kernel<<<KCODES + NTOK, 64, 0, stream>>>(x, cb, dout, FS_XSQ, FS_CSQ);
    zero_kernel<<<KCODES / 256, 256, 0, stream>>>(dout, FS_AVG);
    cvt_kernel<<<2 * QELEMS / 4 / 256, 256, 0, stream>>>(x, cb, ws);
    pass1f<<<dim3(NCHUNK_F, NTOK / 128), 256, 0, stream>>>(ws, dout);
    merge_rows<<<NTOK / 256, 256, 0, stream>>>(dout, FS_PART, NCHUNK_F,
                                               FS_LSE, FS_PLOGP, FS_I1, FS_I2);
    refine<<<NTOK, 64, 0, stream>>>(x, cb, dout, FS_I1, FS_I2, FS_D2);
    colf<<<dim3(NCHUNK_F, NTOK / 128), 256, 0, stream>>>(ws, dout);
    finalize<<<1, 256, 0, stream>>>(dout, FS_AVG, FS_PLOGP, FS_D2);
    gather_kernel<<<NTOK, 128, 0, stream>>>(x, cb, dout);
  } else {
    sq_kernel<<<KCODES + NTOK, 64, 0, stream>>>(x, cb, dout, S_XSQ, S_CSQ);
    zero_kernel<<<KCODES / 256, 256, 0, stream>>>(dout, S_AVG);
    pass1_mfma<<<dim3(NCHUNK, NTOK / 128), 256, 0, stream>>>(x, cb, dout);
    merge_rows<<<NTOK / 256, 256, 0, stream>>>(dout, S_PART, NCHUNK,
                                               S_LSE, S_PLOGP, S_I1, S_I2);
    refine<<<NTOK, 64, 0, stream>>>(x, cb, dout, S_I1, S_I2, S_D2);
    col_mfma<<<dim3(NCHUNK, NTOK / 128), 256, 0, stream>>>(x, cb, dout);
    finalize<<<1, 256, 0, stream>>>(dout, S_AVG, S_PLOGP, S_D2);
    gather_kernel<<<NTOK, 128, 0, stream>>>(x, cb, dout);
  }
}